// Round 4
// baseline (121.424 us; speedup 1.0000x reference)
//
#include <hip/hip_runtime.h>

#define NB    8
#define NH    16384
#define NL    2048
#define F_HR  64
#define F_LR  128
#define OUT_COLS 198   // 64 + 3 + 128 + 3

typedef float vfloat2 __attribute__((ext_vector_type(2)));

// ---------------------------------------------------------------------------
// Kernel A: per high-res point, argmin over its batch's 2048 low-res points.
// Monotone-transformed key: key_j = 0.5*|pl_j|^2 - <ph, pl_j>
//   == (d2_j - |ph|^2)/2 in exact arithmetic -> same argmin as reference d2.
// 3-FMA chain seeded with half_sq from LDS; R1/R3 evidence: all 131072
// argmins match numpy (min-gaps robust to ulp-scale rounding).
// Measured ~19 us, at the VALU roofline for ~6 ops/pair.
// ---------------------------------------------------------------------------
__global__ __launch_bounds__(256) void knn_kernel(
    const float* __restrict__ pos_hr,   // [NB*NH, 3]
    const float* __restrict__ pos_lr,   // [NB*NL, 3]
    int* __restrict__ out_idx)          // [NB*NH] global low-res row index
{
    __shared__ float4 lds[NL];          // 32 KiB: (x, y, z, 0.5*|p|^2)

    const int blocksPerBatch = NH / 256;              // 64
    const int b = blockIdx.x / blocksPerBatch;
    const int rowInBatch = (blockIdx.x % blocksPerBatch) * 256 + threadIdx.x;

    const float* pl = pos_lr + (size_t)b * NL * 3;
    for (int j = threadIdx.x; j < NL; j += 256) {
        float x = pl[j * 3 + 0];
        float y = pl[j * 3 + 1];
        float z = pl[j * 3 + 2];
        lds[j] = make_float4(x, y, z, 0.5f * ((x * x + y * y) + z * z));
    }
    __syncthreads();

    const int hr = b * NH + rowInBatch;
    const float phx = pos_hr[hr * 3 + 0];
    const float phy = pos_hr[hr * 3 + 1];
    const float phz = pos_hr[hr * 3 + 2];

    float best[8];
    int   bi[8];
#pragma unroll
    for (int k = 0; k < 8; ++k) { best[k] = 3.4e38f; bi[k] = k; }

    for (int j = 0; j < NL; j += 8) {
#pragma unroll
        for (int k = 0; k < 8; ++k) {
            float4 c = lds[j + k];
            float d = fmaf(-phz, c.z, fmaf(-phy, c.y, fmaf(-phx, c.x, c.w)));
            if (d < best[k]) { best[k] = d; bi[k] = j + k; }   // strict <: first wins
        }
    }

    float bestv = best[0]; int bestidx = bi[0];
#pragma unroll
    for (int k = 1; k < 8; ++k) {
        if (best[k] < bestv || (best[k] == bestv && bi[k] < bestidx)) {
            bestv = best[k]; bestidx = bi[k];
        }
    }

    out_idx[hr] = b * NL + bestidx;
}

// ---------------------------------------------------------------------------
// Kernel B: assemble flat output as float2 units. Plain stores (nontemporal
// regressed 44->81.5 us in R3: bypassing L2 defeats write-combining).
// Region 0 decoded per-unit u in [0,99):
//   u<32: x_hr pair | u=32: pos_hr[0..1] | u=33: pos_hr[2],x_lr[c=0]
//   u in [34,97): x_lr c=2u-67,c+1 | u=97: x_lr[127],pos_lr[0] | u=98: pos_lr[1..2]
// ---------------------------------------------------------------------------
__global__ __launch_bounds__(256) void assemble_kernel(
    const float* __restrict__ x_hr,     // [NB*NH, 64]
    const float* __restrict__ pos_hr,   // [NB*NH, 3]
    const float* __restrict__ x_lr,     // [NB*NL, 128]
    const float* __restrict__ pos_lr,   // [NB*NL, 3]
    const int* __restrict__ idx,        // [NB*NH]
    float* __restrict__ out)
{
    const int R0 = NB * NH * OUT_COLS;        // 25,952,256 (even)
    const int R1 = R0 + NB * NH * 3;          // 26,345,472 (even)
    const int P0 = R0 / 2;
    const int P1 = R1 / 2;
    const int total2 = (R1 + NB * NH) / 2;    // 13,238,272

    vfloat2* __restrict__ out2 = (vfloat2*)out;
    const int stride = gridDim.x * blockDim.x;

#pragma unroll 4
    for (int t = blockIdx.x * blockDim.x + threadIdx.x;
         t < total2; t += stride) {
        vfloat2 v;
        if (t < P0) {
            const int row = t / 99;
            const int u   = t - row * 99;
            if (u < 32) {
                v = *(const vfloat2*)&x_hr[(row << 6) + (u << 1)];
            } else if (u == 32) {
                v.x = pos_hr[row * 3 + 0];
                v.y = pos_hr[row * 3 + 1];
            } else {
                const int l = idx[row];           // hoisted above x_lr cases
                const int lb = l << 7;            // x_lr row base
                if (u == 33) {
                    v.x = pos_hr[row * 3 + 2];
                    v.y = x_lr[lb];
                } else if (u < 97) {
                    const int c = 2 * u - 67;     // odd offset: two scalar loads
                    v.x = x_lr[lb + c];
                    v.y = x_lr[lb + c + 1];
                } else if (u == 97) {
                    v.x = x_lr[lb + 127];
                    v.y = pos_lr[l * 3 + 0];
                } else {
                    v.x = pos_lr[l * 3 + 1];
                    v.y = pos_lr[l * 3 + 2];
                }
            }
        } else if (t < P1) {
            v.x = 0.0f; v.y = 0.0f;
        } else {
            const int f = 2 * t - R1;             // element offset in batch region
            v.x = (float)(f >> 14);               // NH = 2^14
            v.y = (float)((f + 1) >> 14);
        }
        out2[t] = v;
    }
}

extern "C" void kernel_launch(void* const* d_in, const int* in_sizes, int n_in,
                              void* d_out, int out_size, void* d_ws, size_t ws_size,
                              hipStream_t stream) {
    const float* x_hr   = (const float*)d_in[0];
    const float* pos_hr = (const float*)d_in[1];
    // d_in[2] = batch_hr (int32) — unused, batch is contiguous repeats
    const float* x_lr   = (const float*)d_in[3];
    const float* pos_lr = (const float*)d_in[4];
    // d_in[5] = batch_lr (int32) — unused

    int* idx = (int*)d_ws;                    // NB*NH ints = 512 KiB scratch

    knn_kernel<<<dim3(NB * NH / 256), dim3(256), 0, stream>>>(pos_hr, pos_lr, idx);
    assemble_kernel<<<dim3(3072), dim3(256), 0, stream>>>(
        x_hr, pos_hr, x_lr, pos_lr, idx, (float*)d_out);
}

// Round 5
// 112.339 us; speedup vs baseline: 1.0809x; 1.0809x over previous
//
#include <hip/hip_runtime.h>

#define NB    8
#define NH    16384
#define NL    2048
#define F_HR  64
#define F_LR  128
#define OUT_COLS 198   // 64 + 3 + 128 + 3

// ---------------------------------------------------------------------------
// Kernel A: per high-res point, argmin over its batch's 2048 low-res points.
// Monotone-transformed key: key_j = 0.5*|pl_j|^2 - <ph, pl_j>
//   == (d2_j - |ph|^2)/2 in exact arithmetic -> same argmin as reference d2.
// 3-FMA chain seeded with half_sq from LDS; R3 evidence: all 131072 argmins
// match numpy (min-gaps robust to ulp-scale rounding). Measured ~19 us,
// at the VALU roofline for ~6 ops/pair. DO NOT TOUCH.
// ---------------------------------------------------------------------------
__global__ __launch_bounds__(256) void knn_kernel(
    const float* __restrict__ pos_hr,   // [NB*NH, 3]
    const float* __restrict__ pos_lr,   // [NB*NL, 3]
    int* __restrict__ out_idx)          // [NB*NH] global low-res row index
{
    __shared__ float4 lds[NL];          // 32 KiB: (x, y, z, 0.5*|p|^2)

    const int blocksPerBatch = NH / 256;              // 64
    const int b = blockIdx.x / blocksPerBatch;
    const int rowInBatch = (blockIdx.x % blocksPerBatch) * 256 + threadIdx.x;

    const float* pl = pos_lr + (size_t)b * NL * 3;
    for (int j = threadIdx.x; j < NL; j += 256) {
        float x = pl[j * 3 + 0];
        float y = pl[j * 3 + 1];
        float z = pl[j * 3 + 2];
        lds[j] = make_float4(x, y, z, 0.5f * ((x * x + y * y) + z * z));
    }
    __syncthreads();

    const int hr = b * NH + rowInBatch;
    const float phx = pos_hr[hr * 3 + 0];
    const float phy = pos_hr[hr * 3 + 1];
    const float phz = pos_hr[hr * 3 + 2];

    float best[8];
    int   bi[8];
#pragma unroll
    for (int k = 0; k < 8; ++k) { best[k] = 3.4e38f; bi[k] = k; }

    for (int j = 0; j < NL; j += 8) {
#pragma unroll
        for (int k = 0; k < 8; ++k) {
            float4 c = lds[j + k];
            float d = fmaf(-phz, c.z, fmaf(-phy, c.y, fmaf(-phx, c.x, c.w)));
            if (d < best[k]) { best[k] = d; bi[k] = j + k; }   // strict <: first wins
        }
    }

    float bestv = best[0]; int bestidx = bi[0];
#pragma unroll
    for (int k = 1; k < 8; ++k) {
        if (best[k] < bestv || (best[k] == bestv && bi[k] < bestidx)) {
            bestv = best[k]; bestidx = bi[k];
        }
    }

    out_idx[hr] = b * NL + bestidx;
}

// ---------------------------------------------------------------------------
// Kernel B: EXACT R1 structure — one scalar element per thread, flat
// grid-stride, plain stores. Empirically 44 us (3.4 TB/s); both float2
// restructures (R3 nt, R4 plain+unroll) regressed to 81/107 us. This round
// instruments it: assemble is now the top dispatch, so we get its counters.
// ---------------------------------------------------------------------------
__global__ __launch_bounds__(256) void assemble_kernel(
    const float* __restrict__ x_hr,     // [NB*NH, 64]
    const float* __restrict__ pos_hr,   // [NB*NH, 3]
    const float* __restrict__ x_lr,     // [NB*NL, 128]
    const float* __restrict__ pos_lr,   // [NB*NL, 3]
    const int* __restrict__ idx,        // [NB*NH]
    float* __restrict__ out)
{
    const int R0 = NB * NH * OUT_COLS;        // 25,952,256
    const int R1 = R0 + NB * NH * 3;          // 26,345,472
    const int total = R1 + NB * NH;           // 26,476,544

    for (int i = blockIdx.x * blockDim.x + threadIdx.x;
         i < total; i += gridDim.x * blockDim.x) {
        float v;
        if (i < R0) {
            int row = i / OUT_COLS;
            int col = i - row * OUT_COLS;
            if (col < F_HR) {
                v = x_hr[row * F_HR + col];
            } else if (col < F_HR + 3) {
                v = pos_hr[row * 3 + (col - F_HR)];
            } else if (col < F_HR + 3 + F_LR) {
                int l = idx[row];
                v = x_lr[l * F_LR + (col - (F_HR + 3))];
            } else {
                int l = idx[row];
                v = pos_lr[l * 3 + (col - (F_HR + 3 + F_LR))];
            }
        } else if (i < R1) {
            v = 0.0f;
        } else {
            v = (float)((i - R1) >> 14);      // batch index, NH = 2^14
        }
        out[i] = v;
    }
}

extern "C" void kernel_launch(void* const* d_in, const int* in_sizes, int n_in,
                              void* d_out, int out_size, void* d_ws, size_t ws_size,
                              hipStream_t stream) {
    const float* x_hr   = (const float*)d_in[0];
    const float* pos_hr = (const float*)d_in[1];
    // d_in[2] = batch_hr (int32) — unused, batch is contiguous repeats
    const float* x_lr   = (const float*)d_in[3];
    const float* pos_lr = (const float*)d_in[4];
    // d_in[5] = batch_lr (int32) — unused

    int* idx = (int*)d_ws;                    // NB*NH ints = 512 KiB scratch

    knn_kernel<<<dim3(NB * NH / 256), dim3(256), 0, stream>>>(pos_hr, pos_lr, idx);
    assemble_kernel<<<dim3(3072), dim3(256), 0, stream>>>(
        x_hr, pos_hr, x_lr, pos_lr, idx, (float*)d_out);
}

// Round 7
// 108.355 us; speedup vs baseline: 1.1206x; 1.0368x over previous
//
#include <hip/hip_runtime.h>

#define NB    8
#define NH    16384
#define NL    2048
#define F_HR  64
#define F_LR  128
#define OUT_COLS 198   // 64 + 3 + 128 + 3

// ---------------------------------------------------------------------------
// Kernel A: per high-res point, argmin over its batch's 2048 low-res points.
// Monotone-transformed key: key_j = 0.5*|pl_j|^2 - <ph, pl_j>
//   == (d2_j - |ph|^2)/2 in exact arithmetic -> same argmin as reference d2.
// R3/R5 evidence: all 131072 argmins match numpy. ~19 us, VALU roofline.
// DO NOT TOUCH.
// ---------------------------------------------------------------------------
__global__ __launch_bounds__(256) void knn_kernel(
    const float* __restrict__ pos_hr,   // [NB*NH, 3]
    const float* __restrict__ pos_lr,   // [NB*NL, 3]
    int* __restrict__ out_idx)          // [NB*NH] global low-res row index
{
    __shared__ float4 lds[NL];          // 32 KiB: (x, y, z, 0.5*|p|^2)

    const int blocksPerBatch = NH / 256;              // 64
    const int b = blockIdx.x / blocksPerBatch;
    const int rowInBatch = (blockIdx.x % blocksPerBatch) * 256 + threadIdx.x;

    const float* pl = pos_lr + (size_t)b * NL * 3;
    for (int j = threadIdx.x; j < NL; j += 256) {
        float x = pl[j * 3 + 0];
        float y = pl[j * 3 + 1];
        float z = pl[j * 3 + 2];
        lds[j] = make_float4(x, y, z, 0.5f * ((x * x + y * y) + z * z));
    }
    __syncthreads();

    const int hr = b * NH + rowInBatch;
    const float phx = pos_hr[hr * 3 + 0];
    const float phy = pos_hr[hr * 3 + 1];
    const float phz = pos_hr[hr * 3 + 2];

    float best[8];
    int   bi[8];
#pragma unroll
    for (int k = 0; k < 8; ++k) { best[k] = 3.4e38f; bi[k] = k; }

    for (int j = 0; j < NL; j += 8) {
#pragma unroll
        for (int k = 0; k < 8; ++k) {
            float4 c = lds[j + k];
            float d = fmaf(-phz, c.z, fmaf(-phy, c.y, fmaf(-phx, c.x, c.w)));
            if (d < best[k]) { best[k] = d; bi[k] = j + k; }   // strict <: first wins
        }
    }

    float bestv = best[0]; int bestidx = bi[0];
#pragma unroll
    for (int k = 1; k < 8; ++k) {
        if (best[k] < bestv || (best[k] == bestv && bi[k] < bestidx)) {
            bestv = best[k]; bestidx = bi[k];
        }
    }

    out_idx[hr] = b * NL + bestidx;
}

// ---------------------------------------------------------------------------
// Kernel B: BRANCHLESS assemble. R5 diagnosis: all branchy variants were
// latency-bound (VGPR=8 -> ~1 load in flight -> 1.7 TB/s). Region decode is
// arithmetic + pointer select, the load is unconditional, and the main loop
// has a compile-time trip count (exactly 33) so unrolling puts many
// independent idx->gather chains in flight per wave.
// R6 bug fixed: use plain i/OUT_COLS — compiler emits the correct magic-mul
// for a constant divisor (hand-rolled constant was wrong).
// ---------------------------------------------------------------------------
#define GRID_B   3072
#define NTHREADS (GRID_B * 256)                 // 786,432
// R0 = 8*16384*198 = 25,952,256 = 33 * NTHREADS exactly -> no bounds checks

__device__ __forceinline__ float gather_elem(
    int i,
    const float* __restrict__ x_hr, const float* __restrict__ pos_hr,
    const float* __restrict__ x_lr, const float* __restrict__ pos_lr,
    const int* __restrict__ idx)
{
    const int row = i / OUT_COLS;               // compiler magic-mul
    const int col = i - row * OUT_COLS;
    const int l   = idx[row];                   // unconditional; L1-hot broadcast

    // four candidate addresses (cheap VALU), one selected, one load
    const float* a0 = x_hr   + row * F_HR + col;
    const float* a1 = pos_hr + row * 3    + (col - F_HR);
    const float* a2 = x_lr   + l * F_LR   + (col - (F_HR + 3));
    const float* a3 = pos_lr + l * 3      + (col - (F_HR + 3 + F_LR));

    const float* a = col < F_HR ? a0
                   : col < F_HR + 3 ? a1
                   : col < F_HR + 3 + F_LR ? a2
                   : a3;
    return *a;
}

__global__ __launch_bounds__(256) void assemble_kernel(
    const float* __restrict__ x_hr,     // [NB*NH, 64]
    const float* __restrict__ pos_hr,   // [NB*NH, 3]
    const float* __restrict__ x_lr,     // [NB*NL, 128]
    const float* __restrict__ pos_lr,   // [NB*NL, 3]
    const int* __restrict__ idx,        // [NB*NH]
    float* __restrict__ out)
{
    const int R0 = NB * NH * OUT_COLS;        // 25,952,256
    const int Z  = NB * NH * 3;               // 393,216 zeros after R0
    const int TAIL = Z + NB * NH;             // 524,288 total tail elems

    const int tid = blockIdx.x * blockDim.x + threadIdx.x;

    // main gather region: exactly 33 iterations, no bounds check
#pragma unroll 8
    for (int k = 0; k < 33; ++k) {
        const int i = tid + k * NTHREADS;
        out[i] = gather_elem(i, x_hr, pos_hr, x_lr, pos_lr, idx);
    }

    // tail: zeros + batch-as-float, single branchless iteration
    if (tid < TAIL) {
        const float v = tid < Z ? 0.0f : (float)((tid - Z) >> 14);  // NH = 2^14
        out[R0 + tid] = v;
    }
}

extern "C" void kernel_launch(void* const* d_in, const int* in_sizes, int n_in,
                              void* d_out, int out_size, void* d_ws, size_t ws_size,
                              hipStream_t stream) {
    const float* x_hr   = (const float*)d_in[0];
    const float* pos_hr = (const float*)d_in[1];
    // d_in[2] = batch_hr (int32) — unused, batch is contiguous repeats
    const float* x_lr   = (const float*)d_in[3];
    const float* pos_lr = (const float*)d_in[4];
    // d_in[5] = batch_lr (int32) — unused

    int* idx = (int*)d_ws;                    // NB*NH ints = 512 KiB scratch

    knn_kernel<<<dim3(NB * NH / 256), dim3(256), 0, stream>>>(pos_hr, pos_lr, idx);
    assemble_kernel<<<dim3(GRID_B), dim3(256), 0, stream>>>(
        x_hr, pos_hr, x_lr, pos_lr, idx, (float*)d_out);
}

// Round 8
// 94.876 us; speedup vs baseline: 1.2798x; 1.1421x over previous
//
#include <hip/hip_runtime.h>

#define NB    8
#define NH    16384
#define NL    2048
#define F_HR  64
#define F_LR  128
#define OUT_COLS 198   // 64 + 3 + 128 + 3

// ---------------------------------------------------------------------------
// Kernel A: per high-res point, argmin over its batch's 2048 low-res points.
// Monotone-transformed key: key_j = 0.5*|pl_j|^2 - <ph, pl_j>
//   == (d2_j - |ph|^2)/2 in exact arithmetic -> same argmin as reference d2.
// R3/R5/R7 evidence: all 131072 argmins match numpy. ~19 us, VALU roofline.
// DO NOT TOUCH.
// ---------------------------------------------------------------------------
__global__ __launch_bounds__(256) void knn_kernel(
    const float* __restrict__ pos_hr,   // [NB*NH, 3]
    const float* __restrict__ pos_lr,   // [NB*NL, 3]
    int* __restrict__ out_idx)          // [NB*NH] global low-res row index
{
    __shared__ float4 lds[NL];          // 32 KiB: (x, y, z, 0.5*|p|^2)

    const int blocksPerBatch = NH / 256;              // 64
    const int b = blockIdx.x / blocksPerBatch;
    const int rowInBatch = (blockIdx.x % blocksPerBatch) * 256 + threadIdx.x;

    const float* pl = pos_lr + (size_t)b * NL * 3;
    for (int j = threadIdx.x; j < NL; j += 256) {
        float x = pl[j * 3 + 0];
        float y = pl[j * 3 + 1];
        float z = pl[j * 3 + 2];
        lds[j] = make_float4(x, y, z, 0.5f * ((x * x + y * y) + z * z));
    }
    __syncthreads();

    const int hr = b * NH + rowInBatch;
    const float phx = pos_hr[hr * 3 + 0];
    const float phy = pos_hr[hr * 3 + 1];
    const float phz = pos_hr[hr * 3 + 2];

    float best[8];
    int   bi[8];
#pragma unroll
    for (int k = 0; k < 8; ++k) { best[k] = 3.4e38f; bi[k] = k; }

    for (int j = 0; j < NL; j += 8) {
#pragma unroll
        for (int k = 0; k < 8; ++k) {
            float4 c = lds[j + k];
            float d = fmaf(-phz, c.z, fmaf(-phy, c.y, fmaf(-phx, c.x, c.w)));
            if (d < best[k]) { best[k] = d; bi[k] = j + k; }   // strict <: first wins
        }
    }

    float bestv = best[0]; int bestidx = bi[0];
#pragma unroll
    for (int k = 1; k < 8; ++k) {
        if (best[k] < bestv || (best[k] == bestv && bi[k] < bestidx)) {
            bestv = best[k]; bestidx = bi[k];
        }
    }

    out_idx[hr] = b * NL + bestidx;
}

// ---------------------------------------------------------------------------
// Kernel B: PHASE-SPLIT assemble.
// R7 diagnosis: in-loop idx[row] -> gather is a 2-level dependent VMEM chain;
// consuming the just-issued idx result forces s_waitcnt vmcnt(0), draining
// ALL outstanding loads -> ~1 load in flight -> 1.86 TB/s, VGPR=8.
// Fix: per batch of 11 elements, three fully-unrolled phases:
//   P1: 11 independent idx loads -> ls[]   (no consumer yet)
//   P2: 11 gathers; gather k waits on ls[k] (OLDER than later VMEM -> counted
//       vmcnt(N), loads stay pipelined)
//   P3: 11 coalesced stores.
// Row/col advance incrementally (i += 786432 -> row += 3971(+1), col += 174
// mod 198) -- no per-element division. All arrays fully-unrolled -> registers.
// ---------------------------------------------------------------------------
#define GRID_B   3072
#define NTHREADS (GRID_B * 256)                 // 786,432
// R0 = 8*16384*198 = 25,952,256 = 33 * NTHREADS exactly -> no bounds checks
#define ROW_STEP 3971                           // 786432 / 198
#define COL_STEP 174                            // 786432 % 198
#define BATCH    11                             // 33 = 3 * 11

__global__ __launch_bounds__(256) void assemble_kernel(
    const float* __restrict__ x_hr,     // [NB*NH, 64]
    const float* __restrict__ pos_hr,   // [NB*NH, 3]
    const float* __restrict__ x_lr,     // [NB*NL, 128]
    const float* __restrict__ pos_lr,   // [NB*NL, 3]
    const int* __restrict__ idx,        // [NB*NH]
    float* __restrict__ out)
{
    const int R0 = NB * NH * OUT_COLS;        // 25,952,256
    const int Z  = NB * NH * 3;               // 393,216 zeros after R0
    const int TAIL = Z + NB * NH;             // 524,288 total tail elems

    const int tid = blockIdx.x * blockDim.x + threadIdx.x;

    int row = tid / OUT_COLS;                 // one division per thread
    int col = tid - row * OUT_COLS;

    for (int b = 0; b < 3; ++b) {
        int   rs[BATCH], cs[BATCH], ls[BATCH];
        float vs[BATCH];

        // P1: independent idx loads (+ record row/col), advance running decode
#pragma unroll
        for (int k = 0; k < BATCH; ++k) {
            rs[k] = row;
            cs[k] = col;
            ls[k] = idx[row];
            col += COL_STEP;
            const int carry = (col >= OUT_COLS) ? 1 : 0;
            col -= carry ? OUT_COLS : 0;
            row += ROW_STEP + carry;
        }

        // P2: gathers -- each waits only on its (older) idx result
#pragma unroll
        for (int k = 0; k < BATCH; ++k) {
            const int c = cs[k];
            const float* a =
                  c < F_HR            ? x_hr   + rs[k] * F_HR + c
                : c < F_HR + 3        ? pos_hr + rs[k] * 3    + (c - F_HR)
                : c < F_HR + 3 + F_LR ? x_lr   + ls[k] * F_LR + (c - (F_HR + 3))
                :                       pos_lr + ls[k] * 3    + (c - (F_HR + 3 + F_LR));
            vs[k] = *a;
        }

        // P3: coalesced stores
#pragma unroll
        for (int k = 0; k < BATCH; ++k) {
            out[tid + (b * BATCH + k) * NTHREADS] = vs[k];
        }
    }

    // tail: zeros + batch-as-float, single branchless iteration
    if (tid < TAIL) {
        const float v = tid < Z ? 0.0f : (float)((tid - Z) >> 14);  // NH = 2^14
        out[R0 + tid] = v;
    }
}

extern "C" void kernel_launch(void* const* d_in, const int* in_sizes, int n_in,
                              void* d_out, int out_size, void* d_ws, size_t ws_size,
                              hipStream_t stream) {
    const float* x_hr   = (const float*)d_in[0];
    const float* pos_hr = (const float*)d_in[1];
    // d_in[2] = batch_hr (int32) — unused, batch is contiguous repeats
    const float* x_lr   = (const float*)d_in[3];
    const float* pos_lr = (const float*)d_in[4];
    // d_in[5] = batch_lr (int32) — unused

    int* idx = (int*)d_ws;                    // NB*NH ints = 512 KiB scratch

    knn_kernel<<<dim3(NB * NH / 256), dim3(256), 0, stream>>>(pos_hr, pos_lr, idx);
    assemble_kernel<<<dim3(GRID_B), dim3(256), 0, stream>>>(
        x_hr, pos_hr, x_lr, pos_lr, idx, (float*)d_out);
}